// Round 2
// baseline (1261.190 us; speedup 1.0000x reference)
//
#include <hip/hip_runtime.h>
#include <hip/hip_bf16.h>

// Problem constants (from reference)
constexpr int N  = 50000;   // nodes
constexpr int E  = 800000;  // edges
constexpr int D0 = 64;      // IN_DIM
constexpr int D1 = 128;     // HID_DIM

// ---------------------------------------------------------------------------
// Scatter layer 1: agg1[dst] += x[src] (f32), deg[dst] += 1
// one thread per (edge, feature); wave = one edge's 64 features (coalesced)
// ---------------------------------------------------------------------------
__global__ void k_scatter1(const float* __restrict__ x,
                           const int* __restrict__ src,
                           const int* __restrict__ dst,
                           float* __restrict__ agg,
                           float* __restrict__ deg) {
    unsigned i = blockIdx.x * blockDim.x + threadIdx.x;
    constexpr unsigned total = (unsigned)E * D0;
    if (i >= total) return;
    int e = (int)(i >> 6);        // / 64
    int d = (int)(i & (D0 - 1));  // % 64
    int s = src[e];
    int t = dst[e];
    atomicAdd(&agg[(size_t)t * D0 + d], x[(size_t)s * D0 + d]);
    if (d == 0) atomicAdd(&deg[t], 1.0f);
}

// ---------------------------------------------------------------------------
// Scatter layer 2: agg2[dst] += h[src] (f32)
// ---------------------------------------------------------------------------
__global__ void k_scatter2(const float* __restrict__ h,
                           const int* __restrict__ src,
                           const int* __restrict__ dst,
                           float* __restrict__ agg) {
    unsigned i = blockIdx.x * blockDim.x + threadIdx.x;
    constexpr unsigned total = (unsigned)E * D1;
    if (i >= total) return;
    int e = (int)(i >> 7);        // / 128
    int d = (int)(i & (D1 - 1));  // % 128
    int s = src[e];
    int t = dst[e];
    atomicAdd(&agg[(size_t)t * D1 + d], h[(size_t)s * D1 + d]);
}

// ---------------------------------------------------------------------------
// Dense: out[n,o] = relu?( mean[n,:] @ Wl[o,:] + xin[n,:] @ Wr[o,:] + b[o] )
// mean[n,k] = agg[n,k] / max(deg[n],1)
// block = 128 threads (one per output feature), grid-stride over nodes.
// Weights staged transposed in LDS as bf16 (f32 would exceed 64KB for DIN=128;
// bf16 weight quantization ~0.4% << 2% threshold).
// ---------------------------------------------------------------------------
template<int DIN, bool RELU>
__global__ void k_dense(const float* __restrict__ agg,
                        const float* __restrict__ deg,
                        const float* __restrict__ xin,
                        const float* __restrict__ Wl,
                        const float* __restrict__ Wr,
                        const float* __restrict__ bias,
                        float* __restrict__ out,
                        int n_nodes) {
    constexpr int DOUT = 128;
    __shared__ __hip_bfloat16 WlT[DIN * DOUT];  // [k][o]
    __shared__ __hip_bfloat16 WrT[DIN * DOUT];  // [k][o]

    const int t = threadIdx.x;  // output feature index, 0..127

    // Stage weights transposed: W is [DOUT, DIN] row-major.
    for (int j = t; j < DIN * DOUT; j += 128) {
        int o = j / DIN;
        int k = j - o * DIN;
        WlT[k * DOUT + o] = __float2bfloat16(Wl[j]);
        WrT[k * DOUT + o] = __float2bfloat16(Wr[j]);
    }
    __syncthreads();

    const float bv = bias[t];

    for (int n = blockIdx.x; n < n_nodes; n += gridDim.x) {
        const float invd = 1.0f / fmaxf(deg[n], 1.0f);
        const float* aggrow = agg + (size_t)n * DIN;
        const float* xrow   = xin + (size_t)n * DIN;

        float acc_l = 0.0f;  // mean @ Wl.T
        float acc_r = 0.0f;  // x    @ Wr.T
        #pragma unroll 8
        for (int k = 0; k < DIN; ++k) {
            acc_l += (aggrow[k] * invd) * __bfloat162float(WlT[k * DOUT + t]);
            acc_r += xrow[k]            * __bfloat162float(WrT[k * DOUT + t]);
        }
        float acc = acc_l + acc_r + bv;
        if constexpr (RELU) acc = fmaxf(acc, 0.0f);
        out[(size_t)n * DOUT + t] = acc;
    }
}

// ---------------------------------------------------------------------------
extern "C" void kernel_launch(void* const* d_in, const int* in_sizes, int n_in,
                              void* d_out, int out_size, void* d_ws, size_t ws_size,
                              hipStream_t stream) {
    const float* x   = (const float*)d_in[0];
    const int*   ei  = (const int*)d_in[1];   // [2, E] int32
    const float* W1l = (const float*)d_in[2];
    const float* W1r = (const float*)d_in[3];
    const float* b1  = (const float*)d_in[4];
    const float* W2l = (const float*)d_in[5];
    const float* W2r = (const float*)d_in[6];
    const float* b2  = (const float*)d_in[7];
    float*       out = (float*)d_out;

    const int* src = ei;       // edge_index[0]
    const int* dst = ei + E;   // edge_index[1]

    // Workspace layout (floats), 51.4 MB total:
    //   deg  [N]
    //   aggb [N*D1]  -- agg1 uses the first N*D0 of this, agg2 uses all of it
    //   h    [N*D1]
    float* ws   = (float*)d_ws;
    float* deg  = ws;
    float* aggb = deg + N;
    float* h    = aggb + (size_t)N * D1;
    float* agg1 = aggb;
    float* agg2 = aggb;

    // zero deg + agg1 (contiguous)
    hipMemsetAsync(deg, 0, (size_t)N * (1 + D0) * sizeof(float), stream);

    {
        constexpr unsigned total = (unsigned)E * D0;  // 51.2M
        k_scatter1<<<(total + 255) / 256, 256, 0, stream>>>(x, src, dst, agg1, deg);
    }
    k_dense<D0, /*RELU=*/true>
        <<<2048, 128, 0, stream>>>(agg1, deg, x, W1l, W1r, b1, h, N);

    // zero agg2 (reuses agg1's space; agg1 is dead after dense1)
    hipMemsetAsync(agg2, 0, (size_t)N * D1 * sizeof(float), stream);

    {
        constexpr unsigned total = (unsigned)E * D1;  // 102.4M
        k_scatter2<<<(total + 255) / 256, 256, 0, stream>>>(h, src, dst, agg2);
    }
    k_dense<D1, /*RELU=*/false>
        <<<2048, 128, 0, stream>>>(agg2, deg, h, W2l, W2r, b2, out, N);
}

// Round 3
// 712.927 us; speedup vs baseline: 1.7690x; 1.7690x over previous
//
#include <hip/hip_runtime.h>
#include <hip/hip_bf16.h>

// Problem constants (from reference)
constexpr int N  = 50000;   // nodes
constexpr int E  = 800000;  // edges
constexpr int D0 = 64;      // IN_DIM
constexpr int D1 = 128;     // HID_DIM

// ---------------------------------------------------------------------------
// Scatter layer 1: agg1[dst] += x[src] (f32), deg[dst] += 1
// ---------------------------------------------------------------------------
__global__ void k_scatter1(const float* __restrict__ x,
                           const int* __restrict__ src,
                           const int* __restrict__ dst,
                           float* __restrict__ agg,
                           float* __restrict__ deg) {
    unsigned i = blockIdx.x * blockDim.x + threadIdx.x;
    constexpr unsigned total = (unsigned)E * D0;
    if (i >= total) return;
    int e = (int)(i >> 6);        // / 64
    int d = (int)(i & (D0 - 1));  // % 64
    int s = src[e];
    int t = dst[e];
    atomicAdd(&agg[(size_t)t * D0 + d], x[(size_t)s * D0 + d]);
    if (d == 0) atomicAdd(&deg[t], 1.0f);
}

// ---------------------------------------------------------------------------
// Scatter layer 2: agg2[dst] += h[src] (f32)
// ---------------------------------------------------------------------------
__global__ void k_scatter2(const float* __restrict__ h,
                           const int* __restrict__ src,
                           const int* __restrict__ dst,
                           float* __restrict__ agg) {
    unsigned i = blockIdx.x * blockDim.x + threadIdx.x;
    constexpr unsigned total = (unsigned)E * D1;
    if (i >= total) return;
    int e = (int)(i >> 7);        // / 128
    int d = (int)(i & (D1 - 1));  // % 128
    int s = src[e];
    int t = dst[e];
    atomicAdd(&agg[(size_t)t * D1 + d], h[(size_t)s * D1 + d]);
}

// ---------------------------------------------------------------------------
// Dense: out[n,o] = relu?( mean[n,:] @ Wl[o,:] + x[n,:] @ Wr[o,:] + b[o] )
// Register-tiled: 32 nodes x 128 outputs per block, 256 threads.
// Each thread: 1 output feature x 16 nodes (16 f32 accumulators).
// Activations staged in LDS (f32, float4); LDS reads are wave-broadcast
// (all lanes same address -> conflict-free). Weights via float4 global
// (rows contiguous, L1/L2-hot). One barrier per block.
// ---------------------------------------------------------------------------
template<int DIN, bool RELU>
__global__ __launch_bounds__(256)
void k_dense(const float* __restrict__ agg,
             const float* __restrict__ deg,
             const float* __restrict__ xin,
             const float* __restrict__ Wl,
             const float* __restrict__ Wr,
             const float* __restrict__ bias,
             float* __restrict__ out,
             int n_nodes) {
    constexpr int DOUT = 128;
    constexpr int NT   = 32;     // nodes per block
    __shared__ float sm[NT][DIN];   // mean = agg * invd
    __shared__ float sx[NT][DIN];   // x
    __shared__ float sinv[NT];

    const int tid    = threadIdx.x;
    const int n_base = blockIdx.x * NT;

    if (tid < NT) {
        int n = n_base + tid;
        sinv[tid] = (n < n_nodes) ? (1.0f / fmaxf(deg[n], 1.0f)) : 0.0f;
    }
    __syncthreads();

    // Stage activations: NT*DIN floats each, float4 per iteration.
    constexpr int VECS = NT * DIN / 4;   // 512 (DIN=64) or 1024 (DIN=128)
    for (int v = tid; v < VECS; v += 256) {
        int idx = v * 4;
        int r = idx / DIN;
        int c = idx - r * DIN;
        int n = n_base + r;
        float4 a, b;
        if (n < n_nodes) {
            a = *(const float4*)&agg[(size_t)n * DIN + c];
            float iv = sinv[r];
            a.x *= iv; a.y *= iv; a.z *= iv; a.w *= iv;
            b = *(const float4*)&xin[(size_t)n * DIN + c];
        } else {
            a = make_float4(0.f, 0.f, 0.f, 0.f);
            b = a;
        }
        *(float4*)&sm[r][c] = a;
        *(float4*)&sx[r][c] = b;
    }
    __syncthreads();

    const int o  = tid & (DOUT - 1);   // output feature
    const int nh = tid >> 7;           // node parity (0/1)

    float acc[NT / 2];
    #pragma unroll
    for (int j = 0; j < NT / 2; ++j) acc[j] = 0.0f;

    const float* wlrow = Wl + (size_t)o * DIN;
    const float* wrrow = Wr + (size_t)o * DIN;

    #pragma unroll 2
    for (int k0 = 0; k0 < DIN; k0 += 4) {
        float4 wl = *(const float4*)&wlrow[k0];
        float4 wr = *(const float4*)&wrrow[k0];
        #pragma unroll
        for (int j = 0; j < NT / 2; ++j) {
            int r = j * 2 + nh;
            float4 m  = *(const float4*)&sm[r][k0];
            float4 xv = *(const float4*)&sx[r][k0];
            acc[j] += m.x * wl.x + m.y * wl.y + m.z * wl.z + m.w * wl.w
                    + xv.x * wr.x + xv.y * wr.y + xv.z * wr.z + xv.w * wr.w;
        }
    }

    const float bv = bias[o];
    #pragma unroll
    for (int j = 0; j < NT / 2; ++j) {
        int r = j * 2 + nh;
        int n = n_base + r;
        if (n < n_nodes) {
            float v = acc[j] + bv;
            if constexpr (RELU) v = fmaxf(v, 0.0f);
            out[(size_t)n * DOUT + o] = v;
        }
    }
}

// ---------------------------------------------------------------------------
extern "C" void kernel_launch(void* const* d_in, const int* in_sizes, int n_in,
                              void* d_out, int out_size, void* d_ws, size_t ws_size,
                              hipStream_t stream) {
    const float* x   = (const float*)d_in[0];
    const int*   ei  = (const int*)d_in[1];   // [2, E] int32
    const float* W1l = (const float*)d_in[2];
    const float* W1r = (const float*)d_in[3];
    const float* b1  = (const float*)d_in[4];
    const float* W2l = (const float*)d_in[5];
    const float* W2r = (const float*)d_in[6];
    const float* b2  = (const float*)d_in[7];
    float*       out = (float*)d_out;

    const int* src = ei;       // edge_index[0]
    const int* dst = ei + E;   // edge_index[1]

    // Workspace layout (floats):
    //   deg  [N]
    //   aggb [N*D1]  (agg1 uses first N*D0; agg2 uses all)
    //   h    [N*D1]
    float* ws   = (float*)d_ws;
    float* deg  = ws;
    float* aggb = deg + N;
    float* h    = aggb + (size_t)N * D1;
    float* agg1 = aggb;
    float* agg2 = aggb;

    constexpr int NT = 32;
    const int nblk = (N + NT - 1) / NT;  // 1563

    // zero deg + agg1 (contiguous)
    hipMemsetAsync(deg, 0, (size_t)N * (1 + D0) * sizeof(float), stream);

    {
        constexpr unsigned total = (unsigned)E * D0;  // 51.2M
        k_scatter1<<<(total + 255) / 256, 256, 0, stream>>>(x, src, dst, agg1, deg);
    }
    k_dense<D0, /*RELU=*/true>
        <<<nblk, 256, 0, stream>>>(agg1, deg, x, W1l, W1r, b1, h, N);

    // zero agg2 (reuses agg1's space; agg1 is dead after dense1)
    hipMemsetAsync(agg2, 0, (size_t)N * D1 * sizeof(float), stream);

    {
        constexpr unsigned total = (unsigned)E * D1;  // 102.4M
        k_scatter2<<<(total + 255) / 256, 256, 0, stream>>>(h, src, dst, agg2);
    }
    k_dense<D1, /*RELU=*/false>
        <<<nblk, 256, 0, stream>>>(agg2, deg, h, W2l, W2r, b2, out, N);
}

// Round 4
// 511.730 us; speedup vs baseline: 2.4646x; 1.3932x over previous
//
#include <hip/hip_runtime.h>
#include <hip/hip_bf16.h>

// Problem constants (from reference)
constexpr int N  = 50000;   // nodes
constexpr int E  = 800000;  // edges
constexpr int D0 = 64;      // IN_DIM
constexpr int D1 = 128;     // HID_DIM

// ---------------------------------------------------------------------------
// CSR build step 1: count in-degree (int atomics, cheap)
// ---------------------------------------------------------------------------
__global__ void k_count(const int* __restrict__ dst, int* __restrict__ cnt) {
    int e = blockIdx.x * blockDim.x + threadIdx.x;
    if (e >= E) return;
    atomicAdd(&cnt[dst[e]], 1);
}

// ---------------------------------------------------------------------------
// CSR build step 2: exclusive scan of cnt[N] -> row_ptr[N+1], cursor[N].
// Single block, 1024 threads, chunked + Hillis-Steele on partial sums.
// cnt may alias cursor (each thread reads its chunk before any writes).
// ---------------------------------------------------------------------------
__global__ __launch_bounds__(1024)
void k_scan(const int* __restrict__ cnt, int* __restrict__ row_ptr,
            int* __restrict__ cursor) {
    constexpr int CH = (N + 1023) / 1024;  // 49
    __shared__ int ssum[1024];
    const int t = threadIdx.x;
    const int base = t * CH;

    int vals[CH];
    int local = 0;
    #pragma unroll
    for (int i = 0; i < CH; ++i) {
        int idx = base + i;
        int v = (idx < N) ? cnt[idx] : 0;
        vals[i] = v;
        local += v;
    }
    ssum[t] = local;
    __syncthreads();

    for (int off = 1; off < 1024; off <<= 1) {
        int v   = ssum[t];
        int add = (t >= off) ? ssum[t - off] : 0;
        __syncthreads();
        ssum[t] = v + add;
        __syncthreads();
    }

    int prefix = (t > 0) ? ssum[t - 1] : 0;  // exclusive prefix of this chunk
    #pragma unroll
    for (int i = 0; i < CH; ++i) {
        int idx = base + i;
        if (idx < N) { row_ptr[idx] = prefix; cursor[idx] = prefix; }
        prefix += vals[i];
    }
    if (t == 1023) row_ptr[N] = prefix;  // == E
}

// ---------------------------------------------------------------------------
// CSR build step 3: fill neighbor (source) lists sorted by dst
// ---------------------------------------------------------------------------
__global__ void k_fill(const int* __restrict__ src, const int* __restrict__ dst,
                       int* __restrict__ cursor, int* __restrict__ csr_src) {
    int e = blockIdx.x * blockDim.x + threadIdx.x;
    if (e >= E) return;
    int pos = atomicAdd(&cursor[dst[e]], 1);
    csr_src[pos] = src[e];
}

// ---------------------------------------------------------------------------
// Fused SAGE layer: out[n,o] = relu?( mean_nbr(xin)[n,:] @ Wl[o,:]
//                                   + xin[n,:] @ Wr[o,:] + b[o] )
// Phase A (gather): one wave per node at a time (4 waves x 8 nodes/block);
//   lanes cover features -> each neighbor row read is one coalesced 256/512B
//   load; neighbor ids batch-loaded 64 at a time and broadcast via __shfl.
// Phase B (dense): 256 threads, 1 output x 16 nodes each; LDS activation
//   reads are wave-broadcast (conflict-free); weights float4 from L2.
// ---------------------------------------------------------------------------
template<int DIN, bool RELU>
__global__ __launch_bounds__(256)
void k_layer(const float* __restrict__ xin,
             const int* __restrict__ row_ptr,
             const int* __restrict__ csr_src,
             const float* __restrict__ Wl,
             const float* __restrict__ Wr,
             const float* __restrict__ bias,
             float* __restrict__ out,
             int n_nodes) {
    constexpr int DOUT = 128;
    constexpr int NT   = 32;  // nodes per block
    __shared__ float sm[NT][DIN];  // neighbor mean
    __shared__ float sx[NT][DIN];  // root features

    const int tid  = threadIdx.x;
    const int lane = tid & 63;
    const int wv   = tid >> 6;  // 0..3
    const int n_base = blockIdx.x * NT;

    // ---- Phase A: gather + mean into LDS ----
    #pragma unroll
    for (int i = 0; i < NT / 4; ++i) {
        const int r = wv * (NT / 4) + i;
        const int n = n_base + r;
        if (n < n_nodes) {
            const int start = row_ptr[n];
            const int end   = row_ptr[n + 1];
            const float invd = 1.0f / fmaxf((float)(end - start), 1.0f);
            if constexpr (DIN == 64) {
                float acc = 0.0f;
                for (int b = start; b < end; b += 64) {
                    int nb = (b + lane < end) ? csr_src[b + lane] : 0;
                    const int cnt = min(64, end - b);
                    for (int j = 0; j < cnt; ++j) {
                        int s = __shfl(nb, j);
                        acc += xin[(size_t)s * 64 + lane];
                    }
                }
                sm[r][lane] = acc * invd;
                sx[r][lane] = xin[(size_t)n * 64 + lane];
            } else {
                float2 acc = make_float2(0.0f, 0.0f);
                for (int b = start; b < end; b += 64) {
                    int nb = (b + lane < end) ? csr_src[b + lane] : 0;
                    const int cnt = min(64, end - b);
                    for (int j = 0; j < cnt; ++j) {
                        int s = __shfl(nb, j);
                        float2 v = *(const float2*)&xin[(size_t)s * 128 + 2 * lane];
                        acc.x += v.x; acc.y += v.y;
                    }
                }
                *(float2*)&sm[r][2 * lane] = make_float2(acc.x * invd, acc.y * invd);
                *(float2*)&sx[r][2 * lane] = *(const float2*)&xin[(size_t)n * 128 + 2 * lane];
            }
        } else {
            if constexpr (DIN == 64) {
                sm[r][lane] = 0.0f; sx[r][lane] = 0.0f;
            } else {
                *(float2*)&sm[r][2 * lane] = make_float2(0.f, 0.f);
                *(float2*)&sx[r][2 * lane] = make_float2(0.f, 0.f);
            }
        }
    }
    __syncthreads();

    // ---- Phase B: dense ----
    const int o  = tid & (DOUT - 1);  // output feature
    const int nh = tid >> 7;          // node parity

    float acc[NT / 2];
    #pragma unroll
    for (int j = 0; j < NT / 2; ++j) acc[j] = 0.0f;

    const float* wlrow = Wl + (size_t)o * DIN;
    const float* wrrow = Wr + (size_t)o * DIN;

    #pragma unroll 2
    for (int k0 = 0; k0 < DIN; k0 += 4) {
        float4 wl = *(const float4*)&wlrow[k0];
        float4 wr = *(const float4*)&wrrow[k0];
        #pragma unroll
        for (int j = 0; j < NT / 2; ++j) {
            int r = j * 2 + nh;
            float4 m  = *(const float4*)&sm[r][k0];
            float4 xv = *(const float4*)&sx[r][k0];
            acc[j] += m.x * wl.x + m.y * wl.y + m.z * wl.z + m.w * wl.w
                    + xv.x * wr.x + xv.y * wr.y + xv.z * wr.z + xv.w * wr.w;
        }
    }

    const float bv = bias[o];
    #pragma unroll
    for (int j = 0; j < NT / 2; ++j) {
        int r = j * 2 + nh;
        int n = n_base + r;
        if (n < n_nodes) {
            float v = acc[j] + bv;
            if constexpr (RELU) v = fmaxf(v, 0.0f);
            out[(size_t)n * DOUT + o] = v;
        }
    }
}

// ---------------------------------------------------------------------------
extern "C" void kernel_launch(void* const* d_in, const int* in_sizes, int n_in,
                              void* d_out, int out_size, void* d_ws, size_t ws_size,
                              hipStream_t stream) {
    const float* x   = (const float*)d_in[0];
    const int*   ei  = (const int*)d_in[1];   // [2, E] int32
    const float* W1l = (const float*)d_in[2];
    const float* W1r = (const float*)d_in[3];
    const float* b1  = (const float*)d_in[4];
    const float* W2l = (const float*)d_in[5];
    const float* W2r = (const float*)d_in[6];
    const float* b2  = (const float*)d_in[7];
    float*       out = (float*)d_out;

    const int* src = ei;       // edge_index[0]
    const int* dst = ei + E;   // edge_index[1]

    // Workspace layout (~29.3 MB):
    //   row_ptr int[N+1]
    //   cursor  int[N]      (also used as the count buffer)
    //   csr_src int[E]
    //   h       float[N*D1]
    int*   row_ptr = (int*)d_ws;
    int*   cursor  = row_ptr + (N + 1);
    int*   csr_src = cursor + N;
    float* h       = (float*)(csr_src + E);

    constexpr int NT = 32;
    const int nblk = (N + NT - 1) / NT;  // 1563

    // ---- CSR build (shared by both layers) ----
    hipMemsetAsync(cursor, 0, (size_t)N * sizeof(int), stream);
    k_count<<<(E + 255) / 256, 256, 0, stream>>>(dst, cursor);
    k_scan<<<1, 1024, 0, stream>>>(cursor, row_ptr, cursor);
    k_fill<<<(E + 255) / 256, 256, 0, stream>>>(src, dst, cursor, csr_src);

    // ---- Layer 1: x -> h (ReLU) ----
    k_layer<D0, /*RELU=*/true>
        <<<nblk, 256, 0, stream>>>(x, row_ptr, csr_src, W1l, W1r, b1, h, N);

    // ---- Layer 2: h -> out ----
    k_layer<D1, /*RELU=*/false>
        <<<nblk, 256, 0, stream>>>(h, row_ptr, csr_src, W2l, W2r, b2, out, N);
}

// Round 5
// 396.865 us; speedup vs baseline: 3.1779x; 1.2894x over previous
//
#include <hip/hip_runtime.h>
#include <hip/hip_bf16.h>

// Problem constants (from reference)
constexpr int N  = 50000;   // nodes
constexpr int E  = 800000;  // edges
constexpr int D0 = 64;      // IN_DIM
constexpr int D1 = 128;     // HID_DIM

// ---------------------------------------------------------------------------
// CSR build step 1: count in-degree (int atomics, cheap)
// ---------------------------------------------------------------------------
__global__ void k_count(const int* __restrict__ dst, int* __restrict__ cnt) {
    int e = blockIdx.x * blockDim.x + threadIdx.x;
    if (e >= E) return;
    atomicAdd(&cnt[dst[e]], 1);
}

// ---------------------------------------------------------------------------
// CSR build step 2: exclusive scan of cnt[N] -> row_ptr[N+1], cursor[N].
// Single block, 1024 threads, chunked + Hillis-Steele on partial sums.
// cnt may alias cursor (each thread reads its chunk before any writes).
// ---------------------------------------------------------------------------
__global__ __launch_bounds__(1024)
void k_scan(const int* __restrict__ cnt, int* __restrict__ row_ptr,
            int* __restrict__ cursor) {
    constexpr int CH = (N + 1023) / 1024;  // 49
    __shared__ int ssum[1024];
    const int t = threadIdx.x;
    const int base = t * CH;

    int vals[CH];
    int local = 0;
    #pragma unroll
    for (int i = 0; i < CH; ++i) {
        int idx = base + i;
        int v = (idx < N) ? cnt[idx] : 0;
        vals[i] = v;
        local += v;
    }
    ssum[t] = local;
    __syncthreads();

    for (int off = 1; off < 1024; off <<= 1) {
        int v   = ssum[t];
        int add = (t >= off) ? ssum[t - off] : 0;
        __syncthreads();
        ssum[t] = v + add;
        __syncthreads();
    }

    int prefix = (t > 0) ? ssum[t - 1] : 0;  // exclusive prefix of this chunk
    #pragma unroll
    for (int i = 0; i < CH; ++i) {
        int idx = base + i;
        if (idx < N) { row_ptr[idx] = prefix; cursor[idx] = prefix; }
        prefix += vals[i];
    }
    if (t == 1023) row_ptr[N] = prefix;  // == E
}

// ---------------------------------------------------------------------------
// CSR build step 3: fill neighbor (source) lists sorted by dst
// ---------------------------------------------------------------------------
__global__ void k_fill(const int* __restrict__ src, const int* __restrict__ dst,
                       int* __restrict__ cursor, int* __restrict__ csr_src) {
    int e = blockIdx.x * blockDim.x + threadIdx.x;
    if (e >= E) return;
    int pos = atomicAdd(&cursor[dst[e]], 1);
    csr_src[pos] = src[e];
}

// ---------------------------------------------------------------------------
// Fused SAGE layer: out[n,o] = relu?( mean_nbr(xin)[n,:] @ Wl[o,:]
//                                   + xin[n,:] @ Wr[o,:] + b[o] )
// Phase A (gather): sub-wave groups for memory-level parallelism.
//   DIN=64 : 4 groups x 16 lanes/wave, float4 -> 256B per row load
//   DIN=128: 2 groups x 32 lanes/wave, float4 -> 512B per row load
//   Each group owns one node at a time (all lanes same trip count ->
//   __shfl sources stay convergent). Neighbor loop unrolled x4 with 4
//   independent accumulators -> ~4 loads in flight per group.
// Phase B (dense): 256 threads, 1 output x 16 nodes each; LDS activation
//   reads are wave-broadcast (conflict-free); weights float4 from L2.
// ---------------------------------------------------------------------------
template<int DIN, bool RELU>
__global__ __launch_bounds__(256)
void k_layer(const float* __restrict__ xin,
             const int* __restrict__ row_ptr,
             const int* __restrict__ csr_src,
             const float* __restrict__ Wl,
             const float* __restrict__ Wr,
             const float* __restrict__ bias,
             float* __restrict__ out,
             int n_nodes) {
    constexpr int DOUT  = 128;
    constexpr int NT    = 32;           // nodes per block
    constexpr int GRPSZ = DIN / 4;      // lanes per gather group (16 or 32)
    constexpr int NGRP  = 64 / GRPSZ;   // groups per wave (4 or 2)
    constexpr int NPG   = (NT / 4) / NGRP;  // nodes per group (2 or 4)

    __shared__ float sm[NT][DIN];  // neighbor mean
    __shared__ float sx[NT][DIN];  // root features

    const int tid  = threadIdx.x;
    const int lane = tid & 63;
    const int wv   = tid >> 6;            // 0..3
    const int grp  = lane / GRPSZ;        // group within wave
    const int sub  = lane % GRPSZ;        // lane within group
    const int lanebase = grp * GRPSZ;     // first lane of this group
    const int n_base = blockIdx.x * NT;

    // ---- Phase A: gather + mean into LDS ----
    #pragma unroll
    for (int i = 0; i < NPG; ++i) {
        const int r = wv * (NT / 4) + grp * NPG + i;
        const int n = n_base + r;
        int start = 0, end = 0;
        if (n < n_nodes) { start = row_ptr[n]; end = row_ptr[n + 1]; }

        float4 a0 = make_float4(0.f, 0.f, 0.f, 0.f);
        float4 a1 = a0, a2 = a0, a3 = a0;

        for (int b = start; b < end; b += GRPSZ) {
            int nb = (b + sub < end) ? csr_src[b + sub] : 0;
            const int cnt = min(GRPSZ, end - b);
            int j = 0;
            for (; j + 3 < cnt; j += 4) {
                int s0 = __shfl(nb, lanebase + j);
                int s1 = __shfl(nb, lanebase + j + 1);
                int s2 = __shfl(nb, lanebase + j + 2);
                int s3 = __shfl(nb, lanebase + j + 3);
                float4 v0 = *(const float4*)&xin[(size_t)s0 * DIN + sub * 4];
                float4 v1 = *(const float4*)&xin[(size_t)s1 * DIN + sub * 4];
                float4 v2 = *(const float4*)&xin[(size_t)s2 * DIN + sub * 4];
                float4 v3 = *(const float4*)&xin[(size_t)s3 * DIN + sub * 4];
                a0.x += v0.x; a0.y += v0.y; a0.z += v0.z; a0.w += v0.w;
                a1.x += v1.x; a1.y += v1.y; a1.z += v1.z; a1.w += v1.w;
                a2.x += v2.x; a2.y += v2.y; a2.z += v2.z; a2.w += v2.w;
                a3.x += v3.x; a3.y += v3.y; a3.z += v3.z; a3.w += v3.w;
            }
            for (; j < cnt; ++j) {
                int s0 = __shfl(nb, lanebase + j);
                float4 v0 = *(const float4*)&xin[(size_t)s0 * DIN + sub * 4];
                a0.x += v0.x; a0.y += v0.y; a0.z += v0.z; a0.w += v0.w;
            }
        }

        if (n < n_nodes) {
            const float invd = 1.0f / fmaxf((float)(end - start), 1.0f);
            float4 s;
            s.x = (a0.x + a1.x + a2.x + a3.x) * invd;
            s.y = (a0.y + a1.y + a2.y + a3.y) * invd;
            s.z = (a0.z + a1.z + a2.z + a3.z) * invd;
            s.w = (a0.w + a1.w + a2.w + a3.w) * invd;
            *(float4*)&sm[r][sub * 4] = s;
            *(float4*)&sx[r][sub * 4] = *(const float4*)&xin[(size_t)n * DIN + sub * 4];
        } else {
            float4 z = make_float4(0.f, 0.f, 0.f, 0.f);
            *(float4*)&sm[r][sub * 4] = z;
            *(float4*)&sx[r][sub * 4] = z;
        }
    }
    __syncthreads();

    // ---- Phase B: dense ----
    const int o  = tid & (DOUT - 1);  // output feature
    const int nh = tid >> 7;          // node parity

    float acc[NT / 2];
    #pragma unroll
    for (int j = 0; j < NT / 2; ++j) acc[j] = 0.0f;

    const float* wlrow = Wl + (size_t)o * DIN;
    const float* wrrow = Wr + (size_t)o * DIN;

    #pragma unroll 2
    for (int k0 = 0; k0 < DIN; k0 += 4) {
        float4 wl = *(const float4*)&wlrow[k0];
        float4 wr = *(const float4*)&wrrow[k0];
        #pragma unroll
        for (int j = 0; j < NT / 2; ++j) {
            int r = j * 2 + nh;
            float4 m  = *(const float4*)&sm[r][k0];
            float4 xv = *(const float4*)&sx[r][k0];
            acc[j] += m.x * wl.x + m.y * wl.y + m.z * wl.z + m.w * wl.w
                    + xv.x * wr.x + xv.y * wr.y + xv.z * wr.z + xv.w * wr.w;
        }
    }

    const float bv = bias[o];
    #pragma unroll
    for (int j = 0; j < NT / 2; ++j) {
        int r = j * 2 + nh;
        int n = n_base + r;
        if (n < n_nodes) {
            float v = acc[j] + bv;
            if constexpr (RELU) v = fmaxf(v, 0.0f);
            out[(size_t)n * DOUT + o] = v;
        }
    }
}

// ---------------------------------------------------------------------------
extern "C" void kernel_launch(void* const* d_in, const int* in_sizes, int n_in,
                              void* d_out, int out_size, void* d_ws, size_t ws_size,
                              hipStream_t stream) {
    const float* x   = (const float*)d_in[0];
    const int*   ei  = (const int*)d_in[1];   // [2, E] int32
    const float* W1l = (const float*)d_in[2];
    const float* W1r = (const float*)d_in[3];
    const float* b1  = (const float*)d_in[4];
    const float* W2l = (const float*)d_in[5];
    const float* W2r = (const float*)d_in[6];
    const float* b2  = (const float*)d_in[7];
    float*       out = (float*)d_out;

    const int* src = ei;       // edge_index[0]
    const int* dst = ei + E;   // edge_index[1]

    // Workspace layout (~29.3 MB):
    //   row_ptr int[N+1]
    //   cursor  int[N]      (also used as the count buffer)
    //   csr_src int[E]
    //   h       float[N*D1]
    int*   row_ptr = (int*)d_ws;
    int*   cursor  = row_ptr + (N + 1);
    int*   csr_src = cursor + N;
    float* h       = (float*)(csr_src + E);

    constexpr int NT = 32;
    const int nblk = (N + NT - 1) / NT;  // 1563

    // ---- CSR build (shared by both layers) ----
    hipMemsetAsync(cursor, 0, (size_t)N * sizeof(int), stream);
    k_count<<<(E + 255) / 256, 256, 0, stream>>>(dst, cursor);
    k_scan<<<1, 1024, 0, stream>>>(cursor, row_ptr, cursor);
    k_fill<<<(E + 255) / 256, 256, 0, stream>>>(src, dst, cursor, csr_src);

    // ---- Layer 1: x -> h (ReLU) ----
    k_layer<D0, /*RELU=*/true>
        <<<nblk, 256, 0, stream>>>(x, row_ptr, csr_src, W1l, W1r, b1, h, N);

    // ---- Layer 2: h -> out ----
    k_layer<D1, /*RELU=*/false>
        <<<nblk, 256, 0, stream>>>(h, row_ptr, csr_src, W2l, W2r, b2, out, N);
}